// Round 1
// baseline (1142.619 us; speedup 1.0000x reference)
//
#include <hip/hip_runtime.h>

// CounterFlowNetwork fused kernel for MI355X (gfx950).
// Strategy: each block owns TILE_B=32 batch rows through the ENTIRE network
// (g0 -> 2 sweeps x (8 desc + 8 asc) plates -> head). All matmuls via
// v_mfma_f32_16x16x32_f16 (fp16 in, fp32 accum). Liquid state l[1..8] in LDS
// (f16, XOR-swizzled); gas state g[0..7] in VGPRs at C-frag positions.
// Weights pre-transposed to f16 (WT[n][k]) in d_ws by prep kernels.

typedef _Float16 f16;
typedef _Float16 f16x8 __attribute__((ext_vector_type(8)));
typedef float f32x4 __attribute__((ext_vector_type(4)));

#define TILE_B 32
#define NT 512
#define SLOT 16384            // one [32][256] f16 slot, bytes
#define TMPA_OFF 131072       // after 8 liquid slots
#define LDS_BYTES 147456      // 9 * 16384 = 144 KiB

__device__ __forceinline__ f32x4 mfma16(f16x8 a, f16x8 b, f32x4 c) {
  return __builtin_amdgcn_mfma_f32_16x16x32_f16(a, b, c, 0, 0, 0);
}
__device__ __forceinline__ f32x4 zero4() {
  f32x4 z; z[0] = 0.f; z[1] = 0.f; z[2] = 0.f; z[3] = 0.f; return z;
}

// acc[fr][fc], fr: row block (0..1 -> rows fr*16+..), fc: col frag (w*32+fc*16)
#define ACCQ(A, q) A[(q) >> 3][((q) >> 2) & 1][(q) & 3]

// A [32 x K] f16 in LDS (swizzled, row stride ASTRIDE bytes); B = WT[n][K] f16 global.
template <int K, int ASTRIDE>
__device__ __forceinline__ void gemm32(const char* aBase, const f16* __restrict__ WT,
                                       int w, int lane, f32x4 (&acc)[2][2]) {
  const int l15 = lane & 15, kg = lane >> 4;
  const int sw = (l15 & 7) << 4;
  #pragma unroll
  for (int ks = 0; ks < (K >> 5); ++ks) {
    const int kk = (ks << 5) + (kg << 3);
    f16x8 a0 = *(const f16x8*)(aBase + l15 * ASTRIDE + ((kk * 2) ^ sw));
    f16x8 a1 = *(const f16x8*)(aBase + (16 + l15) * ASTRIDE + ((kk * 2) ^ sw));
    f16x8 b0 = *(const f16x8*)(WT + (size_t)(w * 32 + l15) * K + kk);
    f16x8 b1 = *(const f16x8*)(WT + (size_t)(w * 32 + 16 + l15) * K + kk);
    acc[0][0] = mfma16(a0, b0, acc[0][0]);
    acc[1][0] = mfma16(a1, b0, acc[1][0]);
    acc[0][1] = mfma16(a0, b1, acc[0][1]);
    acc[1][1] = mfma16(a1, b1, acc[1][1]);
  }
}

// write 16 values (C-frag positions) as f16 into swizzled [32][256] LDS buffer
__device__ __forceinline__ void store16(char* buf, int w, int lane, const float* v) {
  const int l15 = lane & 15, kg = lane >> 4;
  #pragma unroll
  for (int q = 0; q < 16; ++q) {
    const int row = ((q >> 3) & 1) * 16 + kg * 4 + (q & 3);
    const int col = w * 32 + (((q >> 2) & 1) << 4) + l15;
    *(f16*)(buf + row * 512 + ((col * 2) ^ ((row & 7) << 4))) = (f16)v[q];
  }
}

__global__ void prep_transpose(const float* __restrict__ src, f16* __restrict__ dst,
                               int K, int N, int Npad) {
  const int t = blockIdx.x * 256 + threadIdx.x;
  if (t >= Npad * K) return;
  const int n = t / K, k = t - n * K;
  const float v = (n < N) ? src[(size_t)k * N + n] : 0.0f;
  dst[t] = (f16)v;
}

__global__ __launch_bounds__(NT, 2)
void cfn_main(const float* __restrict__ x,
              const float* __restrict__ bge, const float* __restrict__ beq,
              const float* __restrict__ btr, const float* __restrict__ bab,
              const float* __restrict__ alphap,
              const float* __restrict__ b1p, const float* __restrict__ b2p,
              const f16* __restrict__ WgeT, const f16* __restrict__ WeqT,
              const f16* __restrict__ WtrT, const f16* __restrict__ WabT,
              const f16* __restrict__ W1T, const f16* __restrict__ W2T,
              float* __restrict__ out) {
  extern __shared__ char smem[];
  const int tid = threadIdx.x;
  const int lane = tid & 63;
  const int w = tid >> 6;
  const int l15 = lane & 15, kg = lane >> 4;
  const int r0 = blockIdx.x * TILE_B;
  const float alpha = alphap[0];
  const int colA = w * 32 + l15;
  const int colB = colA + 16;

  // ---- stage x tile -> LDS f16 [32][512] swizzled (overlaps liquid slots 0..1)
  {
    const int row = tid >> 4;
    const int cb = (tid & 15) << 5;
    const int rs = (row & 7) << 4;
    const float* p = x + (size_t)(r0 + row) * 512 + cb;
    #pragma unroll
    for (int i = 0; i < 4; ++i) {
      float4 u = *(const float4*)(p + i * 8);
      float4 v = *(const float4*)(p + i * 8 + 4);
      f16x8 h;
      h[0] = (f16)u.x; h[1] = (f16)u.y; h[2] = (f16)u.z; h[3] = (f16)u.w;
      h[4] = (f16)v.x; h[5] = (f16)v.y; h[6] = (f16)v.z; h[7] = (f16)v.w;
      *(f16x8*)(smem + row * 1024 + (((cb + i * 8) * 2) ^ rs)) = h;
    }
  }
  __syncthreads();

  // ---- g0 = relu(x @ W_ge + b_ge); replicate into all 8 gas register slots
  float greg[8][16];
  {
    f32x4 acc[2][2] = {{zero4(), zero4()}, {zero4(), zero4()}};
    gemm32<512, 1024>(smem, WgeT, w, lane, acc);
    const float bv0 = bge[colA], bv1 = bge[colB];
    #pragma unroll
    for (int q = 0; q < 16; ++q) {
      float v2 = ACCQ(acc, q) + (((q >> 2) & 1) ? bv1 : bv0);
      v2 = v2 > 0.f ? v2 : 0.f;
      #pragma unroll
      for (int s = 0; s < 8; ++s) greg[s][q] = v2;
    }
  }
  __syncthreads();  // x-buffer reads complete; liquid slot area free

  float E[16], DF[16], DEL[16];

  #pragma unroll 1
  for (int sweep = 0; sweep < 2; ++sweep) {
    // ================= descending liquid sweep: n = 8..1 =================
    #pragma unroll 1
    for (int n = 8; n >= 1; --n) {
      // e = sigmoid(l[n+1] @ W_eq + b_eq)   (l[9] == 0)
      if (n == 8) {
        const float bv0 = beq[colA], bv1 = beq[colB];
        #pragma unroll
        for (int q = 0; q < 16; ++q) {
          const float s2 = ((q >> 2) & 1) ? bv1 : bv0;
          E[q] = 1.f / (1.f + __expf(-s2));
        }
      } else {
        f32x4 acc[2][2] = {{zero4(), zero4()}, {zero4(), zero4()}};
        gemm32<256, 512>(smem + n * SLOT, WeqT, w, lane, acc);
        const float bv0 = beq[colA], bv1 = beq[colB];
        #pragma unroll
        for (int q = 0; q < 16; ++q) {
          const float s2 = ACCQ(acc, q) + (((q >> 2) & 1) ? bv1 : bv0);
          E[q] = 1.f / (1.f + __expf(-s2));
        }
      }
      // df = g[n-1] - e   (gas in registers; static slot via switch)
      switch (n) {
        case 1: { _Pragma("unroll") for (int q = 0; q < 16; ++q) DF[q] = greg[0][q] - E[q]; } break;
        case 2: { _Pragma("unroll") for (int q = 0; q < 16; ++q) DF[q] = greg[1][q] - E[q]; } break;
        case 3: { _Pragma("unroll") for (int q = 0; q < 16; ++q) DF[q] = greg[2][q] - E[q]; } break;
        case 4: { _Pragma("unroll") for (int q = 0; q < 16; ++q) DF[q] = greg[3][q] - E[q]; } break;
        case 5: { _Pragma("unroll") for (int q = 0; q < 16; ++q) DF[q] = greg[4][q] - E[q]; } break;
        case 6: { _Pragma("unroll") for (int q = 0; q < 16; ++q) DF[q] = greg[5][q] - E[q]; } break;
        case 7: { _Pragma("unroll") for (int q = 0; q < 16; ++q) DF[q] = greg[6][q] - E[q]; } break;
        default: { _Pragma("unroll") for (int q = 0; q < 16; ++q) DF[q] = greg[7][q] - E[q]; } break;
      }
      __syncthreads();                       // prior tmpA users done
      store16(smem + TMPA_OFF, w, lane, DF);
      __syncthreads();
      // delta = alpha * (df @ W_tr + b_tr)
      {
        f32x4 acc[2][2] = {{zero4(), zero4()}, {zero4(), zero4()}};
        gemm32<256, 512>(smem + TMPA_OFF, WtrT, w, lane, acc);
        const float bv0 = btr[colA], bv1 = btr[colB];
        #pragma unroll
        for (int q = 0; q < 16; ++q)
          DEL[q] = alpha * (ACCQ(acc, q) + (((q >> 2) & 1) ? bv1 : bv0));
      }
      __syncthreads();                       // tr-GEMM reads of tmpA done
      store16(smem + TMPA_OFF, w, lane, DEL);
      __syncthreads();
      // l[n] = l[n+1] + delta @ W_ab + b_ab
      {
        f32x4 acc[2][2] = {{zero4(), zero4()}, {zero4(), zero4()}};
        gemm32<256, 512>(smem + TMPA_OFF, WabT, w, lane, acc);
        const float bv0 = bab[colA], bv1 = bab[colB];
        char* dst = smem + (n - 1) * SLOT;
        const char* prv = smem + n * SLOT;   // l[n+1] (unused when n==8)
        #pragma unroll
        for (int q = 0; q < 16; ++q) {
          const int row = ((q >> 3) & 1) * 16 + kg * 4 + (q & 3);
          const int col = ((q >> 2) & 1) ? colB : colA;
          const int off = row * 512 + ((col * 2) ^ ((row & 7) << 4));
          float lp = 0.f;
          if (n < 8) lp = (float)(*(const f16*)(prv + off));
          *(f16*)(dst + off) = (f16)(lp + ACCQ(acc, q) + (((q >> 2) & 1) ? bv1 : bv0));
        }
      }
      __syncthreads();                       // l[n] visible for next eq-GEMM
    }
    // ================= ascending gas sweep: n = 1..8 =================
    #pragma unroll 1
    for (int n = 1; n <= 8; ++n) {
      {
        f32x4 acc[2][2] = {{zero4(), zero4()}, {zero4(), zero4()}};
        gemm32<256, 512>(smem + (n - 1) * SLOT, WeqT, w, lane, acc);
        const float bv0 = beq[colA], bv1 = beq[colB];
        #pragma unroll
        for (int q = 0; q < 16; ++q) {
          const float s2 = ACCQ(acc, q) + (((q >> 2) & 1) ? bv1 : bv0);
          E[q] = 1.f / (1.f + __expf(-s2));
        }
      }
      switch (n) {
        case 1: { _Pragma("unroll") for (int q = 0; q < 16; ++q) DF[q] = greg[0][q] - E[q]; } break;
        case 2: { _Pragma("unroll") for (int q = 0; q < 16; ++q) DF[q] = greg[1][q] - E[q]; } break;
        case 3: { _Pragma("unroll") for (int q = 0; q < 16; ++q) DF[q] = greg[2][q] - E[q]; } break;
        case 4: { _Pragma("unroll") for (int q = 0; q < 16; ++q) DF[q] = greg[3][q] - E[q]; } break;
        case 5: { _Pragma("unroll") for (int q = 0; q < 16; ++q) DF[q] = greg[4][q] - E[q]; } break;
        case 6: { _Pragma("unroll") for (int q = 0; q < 16; ++q) DF[q] = greg[5][q] - E[q]; } break;
        case 7: { _Pragma("unroll") for (int q = 0; q < 16; ++q) DF[q] = greg[6][q] - E[q]; } break;
        default: { _Pragma("unroll") for (int q = 0; q < 16; ++q) DF[q] = greg[7][q] - E[q]; } break;
      }
      __syncthreads();                       // prev iter's tr reads done
      store16(smem + TMPA_OFF, w, lane, DF);
      __syncthreads();
      {
        f32x4 acc[2][2] = {{zero4(), zero4()}, {zero4(), zero4()}};
        gemm32<256, 512>(smem + TMPA_OFF, WtrT, w, lane, acc);
        const float bv0 = btr[colA], bv1 = btr[colB];
        #pragma unroll
        for (int q = 0; q < 16; ++q)
          DEL[q] = alpha * (ACCQ(acc, q) + (((q >> 2) & 1) ? bv1 : bv0));
      }
      if (n < 8) {
        switch (n) {
          case 1: { _Pragma("unroll") for (int q = 0; q < 16; ++q) greg[1][q] = greg[0][q] - DEL[q]; } break;
          case 2: { _Pragma("unroll") for (int q = 0; q < 16; ++q) greg[2][q] = greg[1][q] - DEL[q]; } break;
          case 3: { _Pragma("unroll") for (int q = 0; q < 16; ++q) greg[3][q] = greg[2][q] - DEL[q]; } break;
          case 4: { _Pragma("unroll") for (int q = 0; q < 16; ++q) greg[4][q] = greg[3][q] - DEL[q]; } break;
          case 5: { _Pragma("unroll") for (int q = 0; q < 16; ++q) greg[5][q] = greg[4][q] - DEL[q]; } break;
          case 6: { _Pragma("unroll") for (int q = 0; q < 16; ++q) greg[6][q] = greg[5][q] - DEL[q]; } break;
          default: { _Pragma("unroll") for (int q = 0; q < 16; ++q) greg[7][q] = greg[6][q] - DEL[q]; } break;
        }
      } else {
        float G8[16];
        #pragma unroll
        for (int q = 0; q < 16; ++q) G8[q] = greg[7][q] - DEL[q];
        __syncthreads();                     // tr reads of tmpA done
        store16(smem + TMPA_OFF, w, lane, G8);  // g[8] -> tmpA (feats k<256)
      }
    }
  }
  __syncthreads();

  // ---- head: feats = [g8 | l1]; h = relu(feats @ W1 + b1) -> slot1
  {
    f32x4 acc[2][2] = {{zero4(), zero4()}, {zero4(), zero4()}};
    const int sw = (l15 & 7) << 4;
    #pragma unroll
    for (int ks = 0; ks < 16; ++ks) {
      const int kk = (ks << 5) + (kg << 3);
      const char* base = (kk < 256) ? (smem + TMPA_OFF) : smem;  // g8 | l[1]
      const int kl = (kk < 256) ? kk : (kk - 256);
      f16x8 a0 = *(const f16x8*)(base + l15 * 512 + ((kl * 2) ^ sw));
      f16x8 a1 = *(const f16x8*)(base + (16 + l15) * 512 + ((kl * 2) ^ sw));
      f16x8 b0 = *(const f16x8*)(W1T + (size_t)colA * 512 + kk);
      f16x8 b1 = *(const f16x8*)(W1T + (size_t)colB * 512 + kk);
      acc[0][0] = mfma16(a0, b0, acc[0][0]);
      acc[1][0] = mfma16(a1, b0, acc[1][0]);
      acc[0][1] = mfma16(a0, b1, acc[0][1]);
      acc[1][1] = mfma16(a1, b1, acc[1][1]);
    }
    const float bv0 = b1p[colA], bv1 = b1p[colB];
    float H[16];
    #pragma unroll
    for (int q = 0; q < 16; ++q) {
      float v2 = ACCQ(acc, q) + (((q >> 2) & 1) ? bv1 : bv0);
      H[q] = v2 > 0.f ? v2 : 0.f;
    }
    store16(smem + SLOT, w, lane, H);        // h -> slot1 (disjoint from reads)
  }
  __syncthreads();

  // ---- out = h @ W2 + b2  (N=1000, 63 col-frags round-robined over waves)
  {
    const int sw = (l15 & 7) << 4;
    #pragma unroll 1
    for (int f = w; f < 63; f += 8) {
      f32x4 c0 = zero4(), c1 = zero4();
      #pragma unroll
      for (int ks = 0; ks < 8; ++ks) {
        const int kk = (ks << 5) + (kg << 3);
        f16x8 a0 = *(const f16x8*)(smem + SLOT + l15 * 512 + ((kk * 2) ^ sw));
        f16x8 a1 = *(const f16x8*)(smem + SLOT + (16 + l15) * 512 + ((kk * 2) ^ sw));
        f16x8 b = *(const f16x8*)(W2T + (size_t)(f * 16 + l15) * 256 + kk);
        c0 = mfma16(a0, b, c0);
        c1 = mfma16(a1, b, c1);
      }
      const int col = f * 16 + l15;
      if (col < 1000) {
        const float bv = b2p[col];
        #pragma unroll
        for (int j = 0; j < 4; ++j) {
          out[(size_t)(r0 + kg * 4 + j) * 1000 + col] = c0[j] + bv;
          out[(size_t)(r0 + 16 + kg * 4 + j) * 1000 + col] = c1[j] + bv;
        }
      }
    }
  }
}

extern "C" void kernel_launch(void* const* d_in, const int* in_sizes, int n_in,
                              void* d_out, int out_size, void* d_ws, size_t ws_size,
                              hipStream_t stream) {
  const float* x   = (const float*)d_in[0];
  const float* Wge = (const float*)d_in[1];
  const float* bge = (const float*)d_in[2];
  const float* Weq = (const float*)d_in[3];
  const float* beq = (const float*)d_in[4];
  const float* Wtr = (const float*)d_in[5];
  const float* btr = (const float*)d_in[6];
  const float* Wab = (const float*)d_in[7];
  const float* bab = (const float*)d_in[8];
  const float* alp = (const float*)d_in[9];
  const float* W1  = (const float*)d_in[10];
  const float* b1  = (const float*)d_in[11];
  const float* W2  = (const float*)d_in[12];
  const float* b2  = (const float*)d_in[13];
  float* out = (float*)d_out;

  char* ws = (char*)d_ws;
  f16* WgeT = (f16*)(ws + 0);        // 256 x 512
  f16* WeqT = (f16*)(ws + 262144);   // 256 x 256
  f16* WtrT = (f16*)(ws + 393216);   // 256 x 256
  f16* WabT = (f16*)(ws + 524288);   // 256 x 256
  f16* W1T  = (f16*)(ws + 655360);   // 256 x 512
  f16* W2T  = (f16*)(ws + 917504);   // 1008 x 256 (rows >=1000 zero)

  prep_transpose<<<512, 256, 0, stream>>>(Wge, WgeT, 512, 256, 256);
  prep_transpose<<<256, 256, 0, stream>>>(Weq, WeqT, 256, 256, 256);
  prep_transpose<<<256, 256, 0, stream>>>(Wtr, WtrT, 256, 256, 256);
  prep_transpose<<<256, 256, 0, stream>>>(Wab, WabT, 256, 256, 256);
  prep_transpose<<<512, 256, 0, stream>>>(W1, W1T, 512, 256, 256);
  prep_transpose<<<1008, 256, 0, stream>>>(W2, W2T, 256, 1000, 1008);

  (void)hipFuncSetAttribute(reinterpret_cast<const void*>(cfn_main),
                            hipFuncAttributeMaxDynamicSharedMemorySize, LDS_BYTES);
  cfn_main<<<16384 / TILE_B, NT, LDS_BYTES, stream>>>(
      x, bge, beq, btr, bab, alp, b1, b2,
      WgeT, WeqT, WtrT, WabT, W1T, W2T, out);
}